// Round 1
// baseline (107.033 us; speedup 1.0000x reference)
//
#include <hip/hip_runtime.h>
#include <math.h>

// Problem constants (from reference setup_inputs)
constexpr int H = 2048;
constexpr int W = 4096;
constexpr int C = 3;
constexpr float A_CUBIC = -0.5f;

// Keys cubic-convolution kernel, support (-2,2), a=-0.5
__device__ __forceinline__ float cubic_w(float t) {
    float at = fabsf(t);
    float at2 = at * at;
    float at3 = at2 * at;
    float w_inner = (A_CUBIC + 2.0f) * at3 - (A_CUBIC + 3.0f) * at2 + 1.0f;
    float w_outer = A_CUBIC * at3 - 5.0f * A_CUBIC * at2 + 8.0f * A_CUBIC * at - 4.0f * A_CUBIC;
    if (at <= 1.0f) return w_inner;
    if (at < 2.0f)  return w_outer;
    return 0.0f;
}

// Row of the (n_out, 3) spline-upsample matrix for control grid of 3 points,
// with edge taps clamped (accumulated) — matches _spline_upsample_matrix.
__device__ __forceinline__ void bweights3(int idx, int n_out, float w[3]) {
    float u = (float)idx * 2.0f / (float)(n_out - 1);
    float i0 = floorf(u);
    w[0] = 0.0f; w[1] = 0.0f; w[2] = 0.0f;
#pragma unroll
    for (int k = -1; k < 3; ++k) {
        float tap = i0 + (float)k;
        float wt = cubic_w(u - tap);
        int tc = (int)tap;
        tc = tc < 0 ? 0 : (tc > 2 ? 2 : tc);
        w[tc] += wt;
    }
}

__global__ __launch_bounds__(256)
void elastic_warp_kernel(const float* __restrict__ img,
                         const float* __restrict__ dctrl,  // (2,3,3) raw (unscaled)
                         float* __restrict__ out) {
    int idx = blockIdx.x * blockDim.x + threadIdx.x;
    if (idx >= H * W) return;
    int h = idx >> 12;        // / W  (W = 4096)
    int w = idx & (W - 1);    // % W

    // Spline rows for this pixel
    float by[3], bx[3];
    bweights3(h, H, by);
    bweights3(w, W, bx);

    // Displacement: d = By . (5*D) . Bx  for d=0 (dy) and d=1 (dx)
    float d0 = 0.0f, d1 = 0.0f;
#pragma unroll
    for (int y = 0; y < 3; ++y) {
#pragma unroll
        for (int x = 0; x < 3; ++x) {
            float byx = by[y] * bx[x];
            d0 += byx * dctrl[y * 3 + x];
            d1 += byx * dctrl[9 + y * 3 + x];
        }
    }
    d0 *= 5.0f;
    d1 *= 5.0f;

    float yy = (float)h + d0;
    float xx = (float)w + d1;
    float iy0f = floorf(yy);
    float ix0f = floorf(xx);
    float fy = yy - iy0f;
    float fx = xx - ix0f;
    int iy0 = (int)iy0f;
    int ix0 = (int)ix0f;

    float wy[4], wx[4];
    wy[0] = cubic_w(fy + 1.0f);
    wy[1] = cubic_w(fy);
    wy[2] = cubic_w(fy - 1.0f);
    wy[3] = cubic_w(fy - 2.0f);
    wx[0] = cubic_w(fx + 1.0f);
    wx[1] = cubic_w(fx);
    wx[2] = cubic_w(fx - 1.0f);
    wx[3] = cubic_w(fx - 2.0f);

    float acc0 = 0.0f, acc1 = 0.0f, acc2 = 0.0f;
#pragma unroll
    for (int a = 0; a < 4; ++a) {
        int ty = iy0 + a - 1;
        ty = ty < 0 ? 0 : (ty > H - 1 ? H - 1 : ty);
        const float* row = img + (size_t)ty * (W * C);
        float ay = wy[a];
#pragma unroll
        for (int b = 0; b < 4; ++b) {
            int tx = ix0 + b - 1;
            tx = tx < 0 ? 0 : (tx > W - 1 ? W - 1 : tx);
            float wgt = ay * wx[b];
            const float* p = row + tx * C;
            acc0 += wgt * p[0];
            acc1 += wgt * p[1];
            acc2 += wgt * p[2];
        }
    }

    float* o = out + (size_t)idx * C;
    o[0] = acc0;
    o[1] = acc1;
    o[2] = acc2;
}

extern "C" void kernel_launch(void* const* d_in, const int* in_sizes, int n_in,
                              void* d_out, int out_size, void* d_ws, size_t ws_size,
                              hipStream_t stream) {
    const float* img   = (const float*)d_in[0];
    const float* dctrl = (const float*)d_in[1];
    float* out = (float*)d_out;

    int npix = H * W;
    int block = 256;
    int grid = (npix + block - 1) / block;
    elastic_warp_kernel<<<grid, block, 0, stream>>>(img, dctrl, out);
}

// Round 2
// 67.749 us; speedup vs baseline: 1.5798x; 1.5798x over previous
//
#include <hip/hip_runtime.h>
#include <math.h>

constexpr int H = 2048;
constexpr int W = 4096;

// Keys cubic (a = -0.5) pieces, evaluated on the known-positive argument.
__device__ __forceinline__ float k_inner(float t) {   // t in [0,1]:  1.5t^3 - 2.5t^2 + 1
    return fmaf(fmaf(1.5f, t, -2.5f), t * t, 1.0f);
}
__device__ __forceinline__ float k_outer(float t) {   // t in [1,2]: -0.5t^3 + 2.5t^2 - 4t + 2
    return fmaf(fmaf(fmaf(-0.5f, t, 2.5f), t, -4.0f), t, 2.0f);
}
// General branchy version (used once per block for the row weights)
__device__ __forceinline__ float cubic_w(float t) {
    float at = fabsf(t);
    if (at <= 1.0f) return k_inner(at);
    if (at < 2.0f)  return k_outer(at);
    return 0.0f;
}

__global__ __launch_bounds__(256)
void elastic_warp_kernel(const float* __restrict__ img,
                         const float* __restrict__ dctrl,  // (2,3,3) unscaled
                         float* __restrict__ out) {
    // Each block covers 256 consecutive pixels of ONE row (W/256 = 16 blocks/row)
    int h = blockIdx.x >> 4;
    int w = ((blockIdx.x & 15) << 8) | threadIdx.x;

    // ---- block-uniform: by[3] and cy = 5 * (by^T . D) ----
    __shared__ float s_cy[6];   // [0..2] = dy row-contraction, [3..5] = dx
    if (threadIdx.x == 0) {
        float u = (float)(2 * h) / (float)(H - 1);
        float i0 = floorf(u);
        float by0 = 0.0f, by1 = 0.0f, by2 = 0.0f;
#pragma unroll
        for (int k = -1; k < 3; ++k) {
            float tap = i0 + (float)k;
            float wt = cubic_w(u - tap);
            int tc = (int)tap;
            tc = tc < 0 ? 0 : (tc > 2 ? 2 : tc);
            if (tc == 0) by0 += wt; else if (tc == 1) by1 += wt; else by2 += wt;
        }
#pragma unroll
        for (int x = 0; x < 3; ++x) {
            s_cy[x]     = 5.0f * (by0 * dctrl[x] + by1 * dctrl[3 + x] + by2 * dctrl[6 + x]);
            s_cy[3 + x] = 5.0f * (by0 * dctrl[9 + x] + by1 * dctrl[12 + x] + by2 * dctrl[15 + x]);
        }
    }
    __syncthreads();

    // ---- per-thread bx[3] (piecewise, branchless) ----
    float u = (float)(2 * w) / (float)(W - 1);
    bool hi = u >= 1.0f;
    float s = u - (hi ? 1.0f : 0.0f);
    float o1 = k_outer(1.0f + s);
    float is = k_inner(s);
    float i1 = k_inner(1.0f - s);
    float o2 = k_outer(2.0f - s);
    float bx0 = hi ? o1 : (o1 + is);
    float bx1 = hi ? is : i1;
    float bx2 = hi ? (i1 + o2) : o2;

    float d0 = s_cy[0] * bx0 + s_cy[1] * bx1 + s_cy[2] * bx2;
    float d1 = s_cy[3] * bx0 + s_cy[4] * bx1 + s_cy[5] * bx2;

    // ---- sample coordinates & tap weights (branchless Horner) ----
    float yy = (float)h + d0;
    float xx = (float)w + d1;
    float iy0f = floorf(yy);
    float ix0f = floorf(xx);
    float fy = yy - iy0f;
    float fx = xx - ix0f;
    int iy0 = (int)iy0f;
    int ix0 = (int)ix0f;

    float wy0 = k_outer(1.0f + fy), wy1 = k_inner(fy), wy2 = k_inner(1.0f - fy), wy3 = k_outer(2.0f - fy);
    float wx0 = k_outer(1.0f + fx), wx1 = k_inner(fx), wx2 = k_inner(1.0f - fx), wx3 = k_outer(2.0f - fx);
    float wy[4] = {wy0, wy1, wy2, wy3};

    float acc0 = 0.0f, acc1 = 0.0f, acc2 = 0.0f;

    bool interior = (iy0 >= 1) & (iy0 <= H - 3) & (ix0 >= 1) & (ix0 <= W - 3);
    if (interior) {
        // 4 x-taps x 3 channels = 12 contiguous floats per row -> 3 float4 loads
        const float* base = img + ((size_t)(iy0 - 1) * W + (size_t)(ix0 - 1)) * 3;
#pragma unroll
        for (int a = 0; a < 4; ++a) {
            const float4* p4 = (const float4*)(base + (size_t)a * (W * 3));
            float4 v0 = p4[0];
            float4 v1 = p4[1];
            float4 v2 = p4[2];
            float ay = wy[a];
            float w0 = ay * wx0, w1 = ay * wx1, w2 = ay * wx2, w3 = ay * wx3;
            acc0 += w0 * v0.x + w1 * v0.w + w2 * v1.z + w3 * v2.y;
            acc1 += w0 * v0.y + w1 * v1.x + w2 * v1.w + w3 * v2.z;
            acc2 += w0 * v0.z + w1 * v1.y + w2 * v2.x + w3 * v2.w;
        }
    } else {
        float wx[4] = {wx0, wx1, wx2, wx3};
#pragma unroll
        for (int a = 0; a < 4; ++a) {
            int ty = iy0 + a - 1;
            ty = ty < 0 ? 0 : (ty > H - 1 ? H - 1 : ty);
            const float* row = img + (size_t)ty * (W * 3);
            float ay = wy[a];
#pragma unroll
            for (int b = 0; b < 4; ++b) {
                int tx = ix0 + b - 1;
                tx = tx < 0 ? 0 : (tx > W - 1 ? W - 1 : tx);
                float wgt = ay * wx[b];
                const float* p = row + tx * 3;
                acc0 += wgt * p[0];
                acc1 += wgt * p[1];
                acc2 += wgt * p[2];
            }
        }
    }

    float* o = out + ((size_t)h * W + (size_t)w) * 3;
    o[0] = acc0;
    o[1] = acc1;
    o[2] = acc2;
}

extern "C" void kernel_launch(void* const* d_in, const int* in_sizes, int n_in,
                              void* d_out, int out_size, void* d_ws, size_t ws_size,
                              hipStream_t stream) {
    const float* img   = (const float*)d_in[0];
    const float* dctrl = (const float*)d_in[1];
    float* out = (float*)d_out;

    int blocks = (H * W) / 256;
    elastic_warp_kernel<<<blocks, 256, 0, stream>>>(img, dctrl, out);
}

// Round 3
// 66.801 us; speedup vs baseline: 1.6023x; 1.0142x over previous
//
#include <hip/hip_runtime.h>
#include <math.h>

constexpr int H = 2048;
constexpr int W = 4096;
constexpr int ROWSTRIDE = W * 3;   // elements per image row

// Keys cubic (a = -0.5) pieces, evaluated on the known-positive argument.
__device__ __forceinline__ float k_inner(float t) {   // t in [0,1]:  1.5t^3 - 2.5t^2 + 1
    return fmaf(fmaf(1.5f, t, -2.5f), t * t, 1.0f);
}
__device__ __forceinline__ float k_outer(float t) {   // t in [1,2]: -0.5t^3 + 2.5t^2 - 4t + 2
    return fmaf(fmaf(fmaf(-0.5f, t, 2.5f), t, -4.0f), t, 2.0f);
}
__device__ __forceinline__ float cubic_w(float t) {
    float at = fabsf(t);
    if (at <= 1.0f) return k_inner(at);
    if (at < 2.0f)  return k_outer(at);
    return 0.0f;
}

__global__ __launch_bounds__(256)
void elastic_warp_kernel(const float* __restrict__ img,
                         const float* __restrict__ dctrl,  // (2,3,3) unscaled
                         float* __restrict__ out) {
    // Each block covers 256 consecutive pixels of ONE row (W/256 = 16 blocks/row)
    int h = blockIdx.x >> 4;
    int w = ((blockIdx.x & 15) << 8) | threadIdx.x;

    // ---- block-uniform: by[3] and cy = 5 * (by^T . D) ----
    __shared__ float s_cy[6];
    if (threadIdx.x == 0) {
        float u = (float)(2 * h) / (float)(H - 1);
        float i0 = floorf(u);
        float by0 = 0.0f, by1 = 0.0f, by2 = 0.0f;
#pragma unroll
        for (int k = -1; k < 3; ++k) {
            float tap = i0 + (float)k;
            float wt = cubic_w(u - tap);
            int tc = (int)tap;
            tc = tc < 0 ? 0 : (tc > 2 ? 2 : tc);
            if (tc == 0) by0 += wt; else if (tc == 1) by1 += wt; else by2 += wt;
        }
#pragma unroll
        for (int x = 0; x < 3; ++x) {
            s_cy[x]     = 5.0f * (by0 * dctrl[x] + by1 * dctrl[3 + x] + by2 * dctrl[6 + x]);
            s_cy[3 + x] = 5.0f * (by0 * dctrl[9 + x] + by1 * dctrl[12 + x] + by2 * dctrl[15 + x]);
        }
    }
    __syncthreads();

    // ---- per-thread bx[3] (piecewise, branchless) ----
    float u = (float)w * (2.0f / 4095.0f);
    bool hi = u >= 1.0f;
    float s = u - (hi ? 1.0f : 0.0f);
    float o1 = k_outer(1.0f + s);
    float is = k_inner(s);
    float i1 = k_inner(1.0f - s);
    float o2 = k_outer(2.0f - s);
    float bx0 = hi ? o1 : (o1 + is);
    float bx1 = hi ? is : i1;
    float bx2 = hi ? (i1 + o2) : o2;

    float d0 = s_cy[0] * bx0 + s_cy[1] * bx1 + s_cy[2] * bx2;
    float d1 = s_cy[3] * bx0 + s_cy[4] * bx1 + s_cy[5] * bx2;

    // ---- sample coordinates & tap weights (branchless Horner) ----
    float yy = (float)h + d0;
    float xx = (float)w + d1;
    float iy0f = floorf(yy);
    float ix0f = floorf(xx);
    float fy = yy - iy0f;
    float fx = xx - ix0f;
    int iy0 = (int)iy0f;
    int ix0 = (int)ix0f;

    float wy0 = k_outer(1.0f + fy), wy1 = k_inner(fy), wy2 = k_inner(1.0f - fy), wy3 = k_outer(2.0f - fy);
    float wx0 = k_outer(1.0f + fx), wx1 = k_inner(fx), wx2 = k_inner(1.0f - fx), wx3 = k_outer(2.0f - fx);

    float acc0 = 0.0f, acc1 = 0.0f, acc2 = 0.0f;

    bool interior = (iy0 >= 1) & (iy0 <= H - 3) & (ix0 >= 1) & (ix0 <= W - 3);
    if (interior) {
        // 32-bit element offsets -> saddr + voffset addressing
        int off = ((iy0 - 1) * W + (ix0 - 1)) * 3;
        const float* b0 = img + off;
        const float* b1 = b0 + ROWSTRIDE;
        const float* b2 = b1 + ROWSTRIDE;
        const float* b3 = b2 + ROWSTRIDE;

        // Issue ALL 12 loads up front (12 outstanding vmem ops per thread)
        float4 v00 = ((const float4*)b0)[0];
        float4 v01 = ((const float4*)b0)[1];
        float4 v02 = ((const float4*)b0)[2];
        float4 v10 = ((const float4*)b1)[0];
        float4 v11 = ((const float4*)b1)[1];
        float4 v12 = ((const float4*)b1)[2];
        float4 v20 = ((const float4*)b2)[0];
        float4 v21 = ((const float4*)b2)[1];
        float4 v22 = ((const float4*)b2)[2];
        float4 v30 = ((const float4*)b3)[0];
        float4 v31 = ((const float4*)b3)[1];
        float4 v32 = ((const float4*)b3)[2];

        {
            float q0 = wy0 * wx0, q1 = wy0 * wx1, q2 = wy0 * wx2, q3 = wy0 * wx3;
            acc0 = fmaf(q0, v00.x, fmaf(q1, v00.w, fmaf(q2, v01.z, q3 * v02.y)));
            acc1 = fmaf(q0, v00.y, fmaf(q1, v01.x, fmaf(q2, v01.w, q3 * v02.z)));
            acc2 = fmaf(q0, v00.z, fmaf(q1, v01.y, fmaf(q2, v02.x, q3 * v02.w)));
        }
        {
            float q0 = wy1 * wx0, q1 = wy1 * wx1, q2 = wy1 * wx2, q3 = wy1 * wx3;
            acc0 = fmaf(q0, v10.x, fmaf(q1, v10.w, fmaf(q2, v11.z, fmaf(q3, v12.y, acc0))));
            acc1 = fmaf(q0, v10.y, fmaf(q1, v11.x, fmaf(q2, v11.w, fmaf(q3, v12.z, acc1))));
            acc2 = fmaf(q0, v10.z, fmaf(q1, v11.y, fmaf(q2, v12.x, fmaf(q3, v12.w, acc2))));
        }
        {
            float q0 = wy2 * wx0, q1 = wy2 * wx1, q2 = wy2 * wx2, q3 = wy2 * wx3;
            acc0 = fmaf(q0, v20.x, fmaf(q1, v20.w, fmaf(q2, v21.z, fmaf(q3, v22.y, acc0))));
            acc1 = fmaf(q0, v20.y, fmaf(q1, v21.x, fmaf(q2, v21.w, fmaf(q3, v22.z, acc1))));
            acc2 = fmaf(q0, v20.z, fmaf(q1, v21.y, fmaf(q2, v22.x, fmaf(q3, v22.w, acc2))));
        }
        {
            float q0 = wy3 * wx0, q1 = wy3 * wx1, q2 = wy3 * wx2, q3 = wy3 * wx3;
            acc0 = fmaf(q0, v30.x, fmaf(q1, v30.w, fmaf(q2, v31.z, fmaf(q3, v32.y, acc0))));
            acc1 = fmaf(q0, v30.y, fmaf(q1, v31.x, fmaf(q2, v31.w, fmaf(q3, v32.z, acc1))));
            acc2 = fmaf(q0, v30.z, fmaf(q1, v31.y, fmaf(q2, v32.x, fmaf(q3, v32.w, acc2))));
        }
    } else {
        float wy[4] = {wy0, wy1, wy2, wy3};
        float wx[4] = {wx0, wx1, wx2, wx3};
#pragma unroll
        for (int a = 0; a < 4; ++a) {
            int ty = iy0 + a - 1;
            ty = ty < 0 ? 0 : (ty > H - 1 ? H - 1 : ty);
            int rowoff = ty * ROWSTRIDE;
            float ay = wy[a];
#pragma unroll
            for (int b = 0; b < 4; ++b) {
                int tx = ix0 + b - 1;
                tx = tx < 0 ? 0 : (tx > W - 1 ? W - 1 : tx);
                float wgt = ay * wx[b];
                const float* p = img + rowoff + tx * 3;
                acc0 += wgt * p[0];
                acc1 += wgt * p[1];
                acc2 += wgt * p[2];
            }
        }
    }

    int oo = (blockIdx.x * 256 + threadIdx.x) * 3;
    out[oo + 0] = acc0;
    out[oo + 1] = acc1;
    out[oo + 2] = acc2;
}

extern "C" void kernel_launch(void* const* d_in, const int* in_sizes, int n_in,
                              void* d_out, int out_size, void* d_ws, size_t ws_size,
                              hipStream_t stream) {
    const float* img   = (const float*)d_in[0];
    const float* dctrl = (const float*)d_in[1];
    float* out = (float*)d_out;

    int blocks = (H * W) / 256;
    elastic_warp_kernel<<<blocks, 256, 0, stream>>>(img, dctrl, out);
}